// Round 11
// baseline (129.567 us; speedup 1.0000x reference)
//
#include <hip/hip_runtime.h>
#include <hip/hip_bf16.h>

// STDP via the antisymmetric-kernel identity (verified R6, absmax 9.8e-4):
//   out[q,p] = 4w(1-w) * A_SCALE * sum_{b,t} post_s[b,t,q] * Z[b,t,p]
//   Z = pre_tr - pre_rt;  tr = causal decay scan, rt = anti-causal scan.
//   AT[q][b*128+t] = post_spikes (bf16);  BT[p][b*128+t] = Z (bf16)

typedef __attribute__((ext_vector_type(8))) short bf16x8;
typedef __attribute__((ext_vector_type(4))) float f32x4;

#define GN 2048
#define KTOT 2048
#define A_SCALE (0.01f / 16.0f)
#define FST 68   // fbuf dword stride (16B-aligned float4 rows)
#define ZST 66   // zbuf elem stride (8B-aligned packed writes)
#define RST 66   // red dword row stride: quad -> 8*quad mod 32, 2-way = free

#define GLOAD_LDS16(gp, lp) \
    __builtin_amdgcn_global_load_lds((const __attribute__((address_space(1))) void*)(gp), \
                                     (__attribute__((address_space(3))) void*)(lp), 16, 0, 0)

__device__ __forceinline__ unsigned bf16bits(float x) {
    __hip_bfloat16 h = __float2bfloat16(x);
    return (unsigned)*(unsigned short*)&h;
}

// ---------------------------------------------------------------------------
// Kernel 1: transpose (+ double scan for the pre side), float4 global loads.
// grid (32, 16, 2), block 256 (4 waves). z=0: post -> AT, z=1: pre -> BT.
// zbuf overlays fbuf.  LDS 34816 B -> 4 blocks/CU.  (~11.6 us, HBM-bound)
// ---------------------------------------------------------------------------
__global__ __launch_bounds__(256, 4) void trace_kernel(
    const float* __restrict__ pre,
    const float* __restrict__ post,
    const int* __restrict__ dtp,
    __hip_bfloat16* __restrict__ AT,
    __hip_bfloat16* __restrict__ BT)
{
    __shared__ float fbuf[128 * FST];                    // 34816 B, t-major fp32
    __hip_bfloat16* zbuf = (__hip_bfloat16*)fbuf;        // overlay, t-major bf16

    const int tid = threadIdx.x;
    const int w   = tid >> 6;    // wave 0..3
    const int l   = tid & 63;
    const int nq  = tid & 15;    // float4 group along n
    const int tl  = tid >> 4;    // t-row within a 16-row pass
    const int n0  = blockIdx.x * 64;
    const int b   = blockIdx.y;
    const int a   = blockIdx.z;  // 0: post->AT, 1: pre->BT

    int di = dtp[0];
    float dtf = (di > 0 && di < 1000000) ? (float)di : *(const float*)dtp;
    const float decay = __expf(-dtf / 20.0f);

    if (a == 0) {
        #pragma unroll
        for (int pass = 0; pass < 8; ++pass) {
            const int t = pass * 16 + tl;
            float4 v = *(const float4*)&post[((size_t)b * 128 + t) * GN + n0 + 4 * nq];
            uint2 pk;
            pk.x = bf16bits(v.x) | (bf16bits(v.y) << 16);
            pk.y = bf16bits(v.z) | (bf16bits(v.w) << 16);
            *(uint2*)&zbuf[t * ZST + 4 * nq] = pk;
        }
        __syncthreads();
    } else {
        #pragma unroll
        for (int pass = 0; pass < 8; ++pass) {
            const int t = pass * 16 + tl;
            float4 v = *(const float4*)&pre[((size_t)b * 128 + t) * GN + n0 + 4 * nq];
            *(float4*)&fbuf[t * FST + 4 * nq] = v;
        }
        __syncthreads();

        const int t0 = 32 * w;   // this wave's t segment [t0, t0+32)
        float carry = 0.0f;
        #pragma unroll 8
        for (int t = 1; t < t0; ++t)
            carry = decay * carry + fbuf[t * FST + l];
        float z[32];
        #pragma unroll
        for (int j = 0; j < 32; ++j) {
            const int t = t0 + j;
            if (t >= 1) carry = decay * carry + fbuf[t * FST + l];
            z[j] = carry;                     // tr (t=0 -> 0)
        }
        float bc = 0.0f;
        #pragma unroll 8
        for (int t = 127; t >= t0 + 32; --t)
            bc = decay * bc + fbuf[t * FST + l];
        #pragma unroll
        for (int j = 31; j >= 0; --j) {
            const int t = t0 + j;
            bc = decay * bc + fbuf[t * FST + l];
            if (t >= 1) z[j] -= bc;           // Z = tr - rt   (Z[0] = 0)
        }
        __syncthreads();   // all waves done reading fbuf before zbuf overlay
        #pragma unroll
        for (int j = 0; j < 32; ++j)
            zbuf[(t0 + j) * ZST + l] = __float2bfloat16(z[j]);
        __syncthreads();
    }

    __hip_bfloat16* dst = (a == 0) ? AT : BT;
    #pragma unroll
    for (int j = 0; j < 4; ++j) {
        const int c  = tid + 256 * j;   // 0..1023
        const int n  = c >> 4;          // 0..63
        const int tc = c & 15;          // 8-t chunk
        unsigned int vv[8];
        #pragma unroll
        for (int i = 0; i < 8; ++i)
            vv[i] = *(const unsigned short*)&zbuf[(8 * tc + i) * ZST + n];
        uint4 pk;
        pk.x = vv[0] | (vv[1] << 16);
        pk.y = vv[2] | (vv[3] << 16);
        pk.z = vv[4] | (vv[5] << 16);
        pk.w = vv[6] | (vv[7] << 16);
        *(uint4*)(dst + (size_t)(n0 + n) * KTOT + b * 128 + tc * 8) = pk;
    }
}

// ---------------------------------------------------------------------------
// Kernel 2: out = 4w(1-w)*A_SCALE * (AT * BT^T), K=2048, fused epilogue.
// 64x64 tile, grid (32,32), BK=128, K-SPLIT ACROSS WAVES: each wave computes
// the full 64x64 tile over its 32-wide K-quarter (jg = wv*4+quad), acc[4][4].
// Per iter per wave: 8 ds_read_b128 + 16 MFMA -> half R9's LDS-read traffic.
// R10 bugs fixed: (1) LDS now 33792 B (red overlays As+Bs, row stride RST=66)
// -> 4 blocks/CU restored (R10 accidentally declared 64 KB -> 2/CU -> 43 us);
// (2) reduction stride 66: quad stride mod 32 = 8 -> every bank 2-way = free
// (was 4-way on all 32 epilogue stores -> 524288 conflict cycles).
// ---------------------------------------------------------------------------
__global__ __launch_bounds__(256) void stdp_gemm(
    const __hip_bfloat16* __restrict__ AT,
    const __hip_bfloat16* __restrict__ BT,
    const float* __restrict__ W,
    float* __restrict__ out)
{
    __shared__ alignas(16) char smem[33792];                 // 4 blocks/CU
    __hip_bfloat16* As = (__hip_bfloat16*)smem;              // 64 x 128 = 16 KB
    __hip_bfloat16* Bs = (__hip_bfloat16*)(smem + 16384);    // 64 x 128 = 16 KB
    float* red = (float*)smem;                               // 4 x 32 x RST = 33792 B

    const int tid  = threadIdx.x;
    const int lane = tid & 63;
    const int wv   = tid >> 6;          // wave 0..3 = K-quarter
    const int RM   = blockIdx.y * 64;   // q base
    const int CN   = blockIdx.x * 64;   // p base
    const int l15  = lane & 15;
    const int quad = lane >> 4;
    const int jg   = wv * 4 + quad;     // this wave's k-chunk (0..15)

    f32x4 acc[4][4] = {};

    for (int k0 = 0; k0 < KTOT; k0 += 128) {
        __syncthreads();  // previous iter's ds_reads done before overwrite
        // stage A and B: each 64 rows x 16 chunks (16B) = 1024 chunks
        #pragma unroll
        for (int it = 0; it < 4; ++it) {
            const int cbase = it * 256 + wv * 64;      // wave-uniform chunk base
            const int c     = cbase + lane;            // 0..1023
            const int row   = c >> 4;                  // 0..63
            const int kc    = (c & 15) ^ (row & 15);   // XOR swizzle (self-inverse)
            GLOAD_LDS16(AT + (size_t)(RM + row) * KTOT + k0 + kc * 8, As + (size_t)cbase * 8);
            GLOAD_LDS16(BT + (size_t)(CN + row) * KTOT + k0 + kc * 8, Bs + (size_t)cbase * 8);
        }
        __syncthreads();  // vmcnt(0) drain: staged data visible

        // this wave's 32-K slice: fragments at k-chunk jg (slot = jg ^ (row&15))
        bf16x8 af[4], bfr[4];
        #pragma unroll
        for (int i = 0; i < 4; ++i) {
            const int mr = i * 16 + l15;
            af[i]  = *(const bf16x8*)(As + mr * 128 + ((jg ^ l15) * 8));
            bfr[i] = *(const bf16x8*)(Bs + mr * 128 + ((jg ^ l15) * 8));
        }
        #pragma unroll
        for (int i = 0; i < 4; ++i)
            #pragma unroll
            for (int j = 0; j < 4; ++j)
                acc[i][j] = __builtin_amdgcn_mfma_f32_16x16x32_bf16(
                    af[i], bfr[j], acc[i][j], 0, 0, 0);
    }

    // -------- 4-way cross-wave reduction + fused epilogue, two 32-row rounds
    // C/D layout per wave: acc[i][j][r] -> row i*16+quad*4+r, col j*16+l15.
    #pragma unroll
    for (int h = 0; h < 2; ++h) {
        __syncthreads();   // round 0: K-loop ds_reads done; round 1: prev round read
        #pragma unroll
        for (int i2 = 0; i2 < 2; ++i2) {
            const int i  = 2 * h + i2;
            const int lr = i2 * 16 + quad * 4;         // local row base 0..31
            #pragma unroll
            for (int r = 0; r < 4; ++r)
                #pragma unroll
                for (int j = 0; j < 4; ++j)
                    red[wv * 32 * RST + (lr + r) * RST + j * 16 + l15] = acc[i][j][r];
        }
        __syncthreads();
        // each wave outputs rows [h*32 + wv*8, +8), col = lane
        #pragma unroll
        for (int r2 = 0; r2 < 8; ++r2) {
            const int lrr = wv * 8 + r2;               // 0..31
            float v = red[lrr * RST + lane]
                    + red[32 * RST + lrr * RST + lane]
                    + red[64 * RST + lrr * RST + lane]
                    + red[96 * RST + lrr * RST + lane];
            const int q = RM + h * 32 + lrr;
            const int p = CN + lane;
            const float w  = W[(size_t)q * GN + p];
            const float wf = 4.0f * w * (1.0f - w);
            out[(size_t)q * GN + p] = wf * A_SCALE * v;
        }
    }
}

extern "C" void kernel_launch(void* const* d_in, const int* in_sizes, int n_in,
                              void* d_out, int out_size, void* d_ws, size_t ws_size,
                              hipStream_t stream) {
    const float* W    = (const float*)d_in[0];  // [2048][2048]
    const float* pre  = (const float*)d_in[1];  // [16][128][2048]
    const float* post = (const float*)d_in[2];  // [16][128][2048]
    const int*   dt   = (const int*)d_in[3];
    float* out = (float*)d_out;

    __hip_bfloat16* AT = (__hip_bfloat16*)d_ws;            // 8 MB
    __hip_bfloat16* BT = AT + (size_t)GN * KTOT;           // +8 MB

    trace_kernel<<<dim3(32, 16, 2), 256, 0, stream>>>(pre, post, dt, AT, BT);
    stdp_gemm<<<dim3(32, 32), 256, 0, stream>>>(AT, BT, W, out);
}

// Round 12
// 121.077 us; speedup vs baseline: 1.0701x; 1.0701x over previous
//
#include <hip/hip_runtime.h>
#include <hip/hip_bf16.h>

// STDP via the antisymmetric-kernel identity (verified R6, absmax 9.8e-4):
//   out[q,p] = 4w(1-w) * A_SCALE * sum_{b,t} post_s[b,t,q] * Z[b,t,p]
//   Z = pre_tr - pre_rt;  tr = causal decay scan, rt = anti-causal scan.
//   AT[q][b*128+t] = post_spikes (bf16);  BT[p][b*128+t] = Z (bf16)

typedef __attribute__((ext_vector_type(8))) short bf16x8;
typedef __attribute__((ext_vector_type(4))) float f32x4;

#define GN 2048
#define KTOT 2048
#define A_SCALE (0.01f / 16.0f)
#define FST 68   // fbuf dword stride (16B-aligned float4 rows)
#define ZST 66   // zbuf elem stride (8B-aligned packed writes)
#define RST 36   // reduce dword row stride: quad -> 16*quad mod 32, 2-way = free

#define GLOAD_LDS16(gp, lp) \
    __builtin_amdgcn_global_load_lds((const __attribute__((address_space(1))) void*)(gp), \
                                     (__attribute__((address_space(3))) void*)(lp), 16, 0, 0)

__device__ __forceinline__ unsigned bf16bits(float x) {
    __hip_bfloat16 h = __float2bfloat16(x);
    return (unsigned)*(unsigned short*)&h;
}

// ---------------------------------------------------------------------------
// Kernel 1: transpose (+ double scan for the pre side), float4 global loads.
// grid (32, 16, 2), block 256 (4 waves). z=0: post -> AT, z=1: pre -> BT.
// zbuf overlays fbuf.  LDS 34816 B -> 4 blocks/CU.  (~12 us, near HBM floor)
// ---------------------------------------------------------------------------
__global__ __launch_bounds__(256, 4) void trace_kernel(
    const float* __restrict__ pre,
    const float* __restrict__ post,
    const int* __restrict__ dtp,
    __hip_bfloat16* __restrict__ AT,
    __hip_bfloat16* __restrict__ BT)
{
    __shared__ float fbuf[128 * FST];                    // 34816 B, t-major fp32
    __hip_bfloat16* zbuf = (__hip_bfloat16*)fbuf;        // overlay, t-major bf16

    const int tid = threadIdx.x;
    const int w   = tid >> 6;    // wave 0..3
    const int l   = tid & 63;
    const int nq  = tid & 15;    // float4 group along n
    const int tl  = tid >> 4;    // t-row within a 16-row pass
    const int n0  = blockIdx.x * 64;
    const int b   = blockIdx.y;
    const int a   = blockIdx.z;  // 0: post->AT, 1: pre->BT

    int di = dtp[0];
    float dtf = (di > 0 && di < 1000000) ? (float)di : *(const float*)dtp;
    const float decay = __expf(-dtf / 20.0f);

    if (a == 0) {
        #pragma unroll
        for (int pass = 0; pass < 8; ++pass) {
            const int t = pass * 16 + tl;
            float4 v = *(const float4*)&post[((size_t)b * 128 + t) * GN + n0 + 4 * nq];
            uint2 pk;
            pk.x = bf16bits(v.x) | (bf16bits(v.y) << 16);
            pk.y = bf16bits(v.z) | (bf16bits(v.w) << 16);
            *(uint2*)&zbuf[t * ZST + 4 * nq] = pk;
        }
        __syncthreads();
    } else {
        #pragma unroll
        for (int pass = 0; pass < 8; ++pass) {
            const int t = pass * 16 + tl;
            float4 v = *(const float4*)&pre[((size_t)b * 128 + t) * GN + n0 + 4 * nq];
            *(float4*)&fbuf[t * FST + 4 * nq] = v;
        }
        __syncthreads();

        const int t0 = 32 * w;   // this wave's t segment [t0, t0+32)
        float carry = 0.0f;
        #pragma unroll 8
        for (int t = 1; t < t0; ++t)
            carry = decay * carry + fbuf[t * FST + l];
        float z[32];
        #pragma unroll
        for (int j = 0; j < 32; ++j) {
            const int t = t0 + j;
            if (t >= 1) carry = decay * carry + fbuf[t * FST + l];
            z[j] = carry;                     // tr (t=0 -> 0)
        }
        float bc = 0.0f;
        #pragma unroll 8
        for (int t = 127; t >= t0 + 32; --t)
            bc = decay * bc + fbuf[t * FST + l];
        #pragma unroll
        for (int j = 31; j >= 0; --j) {
            const int t = t0 + j;
            bc = decay * bc + fbuf[t * FST + l];
            if (t >= 1) z[j] -= bc;           // Z = tr - rt   (Z[0] = 0)
        }
        __syncthreads();   // all waves done reading fbuf before zbuf overlay
        #pragma unroll
        for (int j = 0; j < 32; ++j)
            zbuf[(t0 + j) * ZST + l] = __float2bfloat16(z[j]);
        __syncthreads();
    }

    __hip_bfloat16* dst = (a == 0) ? AT : BT;
    #pragma unroll
    for (int j = 0; j < 4; ++j) {
        const int c  = tid + 256 * j;   // 0..1023
        const int n  = c >> 4;          // 0..63
        const int tc = c & 15;          // 8-t chunk
        unsigned int vv[8];
        #pragma unroll
        for (int i = 0; i < 8; ++i)
            vv[i] = *(const unsigned short*)&zbuf[(8 * tc + i) * ZST + n];
        uint4 pk;
        pk.x = vv[0] | (vv[1] << 16);
        pk.y = vv[2] | (vv[3] << 16);
        pk.z = vv[4] | (vv[5] << 16);
        pk.w = vv[6] | (vv[7] << 16);
        *(uint4*)(dst + (size_t)(n0 + n) * KTOT + b * 128 + tc * 8) = pk;
    }
}

// ---------------------------------------------------------------------------
// Kernel 2: out = 4w(1-w)*A_SCALE * (AT * BT^T), IN-BLOCK split-K.
// 512 threads (8 waves), grid (32,16) = 512 blocks = 2 blocks/CU.
// Wave-group g = waves 4g..4g+3 runs the R5-proven 128x64-tile BK=64 K-loop
// over K-half [g*1024, g*1024+1024) in its own 24 KB LDS region (16 iters,
// lockstep block barriers).  This is the fastest measured per-work config
// (R5: ~24 us-equiv; R6: ~27 us + 12.5 us combine) with the combine's 64 MB
// HBM round-trip replaced by an in-LDS reduction (~66 KB/block, free).
// Drain coverage: 4 waves/SIMD in 2 independent blocks -> 2 runnable waves
// per SIMD during the other block's barrier drain (m97 regime, not R8's).
// Epilogue reduce: group 1 parks acc at row stride RST=36 dwords
// (quad -> 16*quad mod 32: every bank exactly 2-way = free), group 0 adds,
// applies softbound, writes.  LDS 48 KB, VGPR ~70.
// ---------------------------------------------------------------------------
__global__ __launch_bounds__(512) void stdp_gemm(
    const __hip_bfloat16* __restrict__ AT,
    const __hip_bfloat16* __restrict__ BT,
    const float* __restrict__ W,
    float* __restrict__ out)
{
    __shared__ alignas(16) char smem[49152];   // 2 x (As 16K + Bs 8K); reduce overlay

    const int tid  = threadIdx.x;
    const int lane = tid & 63;
    const int wv8  = tid >> 6;          // wave 0..7
    const int grp  = wv8 >> 2;          // K-half 0/1
    const int wv   = wv8 & 3;           // wave within group
    const int wm   = (wv >> 1) * 64;    // {0,64}
    const int wn   = (wv & 1) * 32;     // {0,32}
    const int RM   = blockIdx.y * 128;  // q base
    const int CN   = blockIdx.x * 64;   // p base
    const int l15  = lane & 15;
    const int quad = lane >> 4;

    __hip_bfloat16* Ag = (__hip_bfloat16*)(smem + grp * 24576);          // 128x64
    __hip_bfloat16* Bg = (__hip_bfloat16*)(smem + grp * 24576 + 16384);  // 64x64

    f32x4 acc[4][2] = {};

    const int K0 = grp * 1024;
    for (int k0 = K0; k0 < K0 + 1024; k0 += 64) {
        __syncthreads();  // previous iter's ds_reads done before overwrite
        // stage A: 128 rows x 8 chunks = 1024 chunks over (it, wv, lane)
        #pragma unroll
        for (int it = 0; it < 4; ++it) {
            const int cbase = it * 256 + wv * 64;      // wave-uniform chunk base
            const int c     = cbase + lane;            // 0..1023
            const int row   = c >> 3;                  // 0..127
            const int kc    = (c & 7) ^ (row & 7);     // XOR swizzle (self-inverse)
            GLOAD_LDS16(AT + (size_t)(RM + row) * KTOT + k0 + kc * 8, Ag + (size_t)cbase * 8);
        }
        // stage B: 64 rows x 8 chunks = 512 chunks
        #pragma unroll
        for (int it = 0; it < 2; ++it) {
            const int cbase = it * 256 + wv * 64;
            const int c     = cbase + lane;            // 0..511
            const int row   = c >> 3;                  // 0..63
            const int kc    = (c & 7) ^ (row & 7);
            GLOAD_LDS16(BT + (size_t)(CN + row) * KTOT + k0 + kc * 8, Bg + (size_t)cbase * 8);
        }
        __syncthreads();  // vmcnt(0) drain: staged data visible

        #pragma unroll
        for (int kk = 0; kk < 64; kk += 32) {
            const int jg = (kk >> 3) + quad;           // k-chunk 0..3 / 4..7
            bf16x8 af[4], bfr[2];
            #pragma unroll
            for (int i = 0; i < 4; ++i) {
                const int mr = wm + i * 16 + l15;
                af[i] = *(const bf16x8*)(Ag + mr * 64 + ((jg ^ (mr & 7)) * 8));
            }
            #pragma unroll
            for (int j = 0; j < 2; ++j) {
                const int nr = wn + j * 16 + l15;
                bfr[j] = *(const bf16x8*)(Bg + nr * 64 + ((jg ^ (nr & 7)) * 8));
            }
            #pragma unroll
            for (int i = 0; i < 4; ++i)
                #pragma unroll
                for (int j = 0; j < 2; ++j)
                    acc[i][j] = __builtin_amdgcn_mfma_f32_16x16x32_bf16(
                        af[i], bfr[j], acc[i][j], 0, 0, 0);
        }
    }

    // -------- in-LDS split-K reduction + fused epilogue --------
    // C/D layout: acc[i][j][r] -> local row i*16+quad*4+r (0..63 within the
    // wave's 64x32 sub-tile), local col j*16+l15 (0..31).
    float* red = (float*)smem;                 // 4 waves x 64 rows x RST dwords
    const int rbase = wv * 64 * RST;           // 9216 B/wave, 36864 B total
    __syncthreads();                           // K-loop ds_reads fully drained
    if (grp == 1) {
        #pragma unroll
        for (int i = 0; i < 4; ++i)
            #pragma unroll
            for (int r = 0; r < 4; ++r)
                #pragma unroll
                for (int j = 0; j < 2; ++j)
                    red[rbase + (i * 16 + quad * 4 + r) * RST + j * 16 + l15] = acc[i][j][r];
    }
    __syncthreads();
    if (grp == 0) {
        #pragma unroll
        for (int i = 0; i < 4; ++i) {
            #pragma unroll
            for (int r = 0; r < 4; ++r) {
                const int q = RM + wm + i * 16 + quad * 4 + r;
                #pragma unroll
                for (int j = 0; j < 2; ++j) {
                    const int p = CN + wn + j * 16 + l15;
                    float v = acc[i][j][r]
                            + red[rbase + (i * 16 + quad * 4 + r) * RST + j * 16 + l15];
                    const float w  = W[(size_t)q * GN + p];
                    const float wf = 4.0f * w * (1.0f - w);
                    out[(size_t)q * GN + p] = wf * A_SCALE * v;
                }
            }
        }
    }
}

extern "C" void kernel_launch(void* const* d_in, const int* in_sizes, int n_in,
                              void* d_out, int out_size, void* d_ws, size_t ws_size,
                              hipStream_t stream) {
    const float* W    = (const float*)d_in[0];  // [2048][2048]
    const float* pre  = (const float*)d_in[1];  // [16][128][2048]
    const float* post = (const float*)d_in[2];  // [16][128][2048]
    const int*   dt   = (const int*)d_in[3];
    float* out = (float*)d_out;

    __hip_bfloat16* AT = (__hip_bfloat16*)d_ws;            // 8 MB
    __hip_bfloat16* BT = AT + (size_t)GN * KTOT;           // +8 MB

    trace_kernel<<<dim3(32, 16, 2), 256, 0, stream>>>(pre, post, dt, AT, BT);
    stdp_gemm<<<dim3(32, 16), 512, 0, stream>>>(AT, BT, W, out);
}